// Round 1
// baseline (237.911 us; speedup 1.0000x reference)
//
#include <hip/hip_runtime.h>
#include <math.h>

typedef _Float16 half8  __attribute__((ext_vector_type(8)));
typedef _Float16 half4v __attribute__((ext_vector_type(4)));
typedef _Float16 half2v __attribute__((ext_vector_type(2)));
typedef float    f32x4  __attribute__((ext_vector_type(4)));

// swizzled-weight offsets in halfs inside d_ws
#define W1OFF 0        // 16 MT-tiles * 64 lanes * 8 = 8192 halfs (K padded 2->32)
#define W2OFF 8192     // 8 kkb * 16 MT * 64 * 8 = 65536
#define W3OFF 73728    // 65536
#define W4OFF 139264   // 8 kkb * 64 * 8 = 4096 (N padded 3->16)
#define SWTOT 143360
#define OUT_PIX (16*128*128)

// ---------------- prep: swizzle weights (fp32 -> f16 frag-contiguous) + dx/dy tail ----
__global__ void inr_prep(const float* __restrict__ W1, const float* __restrict__ W2,
                         const float* __restrict__ W3, const float* __restrict__ W4,
                         const int* __restrict__ sidx, const float* __restrict__ sv,
                         _Float16* __restrict__ wsw, float* __restrict__ outtail)
{
    int tid = blockIdx.x * 256 + threadIdx.x;
    if (tid < 16) {
        int si = sidx[tid];
        outtail[tid]      = sv[2*si + 1];   // dx = shift[:,1]
        outtail[16 + tid] = sv[2*si + 0];   // dy = shift[:,0]
    }
    if (tid >= SWTOT) return;
    int kind, rel;
    if      (tid < W2OFF) { kind = 0; rel = tid; }
    else if (tid < W3OFF) { kind = 1; rel = tid - W2OFF; }
    else if (tid < W4OFF) { kind = 2; rel = tid - W3OFF; }
    else                  { kind = 3; rel = tid - W4OFF; }
    int j    = rel & 7;
    int lane = (rel >> 3) & 63;
    int blk  = rel >> 9;
    int q = lane >> 4, ln = lane & 15;
    float val;
    if (kind == 3) {                       // W4: A[m][k] = W4[k][m], m<3 else 0
        int m = ln;
        int k = blk * 32 + q * 8 + j;
        val = (m < 3) ? W4[k*3 + m] : 0.0f;
    } else {
        int MT = blk & 15, kkb = blk >> 4;
        int m = MT*16 + ln;
        int k = kkb*32 + q*8 + j;
        if      (kind == 0) val = (k < 2) ? W1[k*256 + m] : 0.0f;
        else if (kind == 1) val = W2[k*256 + m];
        else                val = W3[k*256 + m];
    }
    wsw[tid] = (_Float16)val;
}

// ---------------- fused MLP ----------------
// LDS activation layout: element (pixel, hid) lives at
//   hbuf[pixel*256 + ((hid>>3 + pixel)&31)*8 + (hid&7)]   (granule swizzle, stride 256)
template<int NKK>
__device__ __forceinline__ void do_layer(const half8* __restrict__ Asw,
                                         const float* __restrict__ bias,
                                         _Float16* hbuf, int w, int q, int ln, int lane)
{
    f32x4 acc[4][8];
#pragma unroll
    for (int mt = 0; mt < 4; ++mt)
#pragma unroll
        for (int nt = 0; nt < 8; ++nt)
            acc[mt][nt] = (f32x4){0.f, 0.f, 0.f, 0.f};

#pragma unroll
    for (int kkb = 0; kkb < NKK; ++kkb) {
        half8 aw[4];                                   // weights: global dwordx4, L2-hot
#pragma unroll
        for (int mt = 0; mt < 4; ++mt)
            aw[mt] = Asw[(kkb*16 + 4*w + mt)*64 + lane];
        half8 bf[8];                                   // activations: ds_read_b128
#pragma unroll
        for (int nt = 0; nt < 8; ++nt) {
            int pixel = 16*nt + ln;
            int slot  = (kkb*4 + q + pixel) & 31;
            bf[nt] = *(const half8*)&hbuf[pixel*256 + slot*8];
        }
#pragma unroll
        for (int nt = 0; nt < 8; ++nt)
#pragma unroll
            for (int mt = 0; mt < 4; ++mt)
                acc[mt][nt] = __builtin_amdgcn_mfma_f32_16x16x32_f16(aw[mt], bf[nt], acc[mt][nt], 0, 0, 0);
    }
    __syncthreads();                                   // all reads of hbuf done
    // epilogue: bias + relu + f16 cast; lane holds 4 consecutive hids -> one b64 write
#pragma unroll
    for (int mt = 0; mt < 4; ++mt) {
        int hid0 = 64*w + 16*mt + 4*q;
        f32x4 bv = *(const f32x4*)&bias[hid0];
        int g = hid0 >> 3;
        int o = hid0 & 7;
#pragma unroll
        for (int nt = 0; nt < 8; ++nt) {
            int pixel = 16*nt + ln;
            f32x4 a = acc[mt][nt];
            half4v hv;
            hv[0] = (_Float16)fmaxf(a[0] + bv[0], 0.f);
            hv[1] = (_Float16)fmaxf(a[1] + bv[1], 0.f);
            hv[2] = (_Float16)fmaxf(a[2] + bv[2], 0.f);
            hv[3] = (_Float16)fmaxf(a[3] + bv[3], 0.f);
            int slot = (g + pixel) & 31;
            *(half4v*)&hbuf[pixel*256 + slot*8 + o] = hv;
        }
    }
    __syncthreads();
}

__launch_bounds__(256, 2)
__global__ void inr_fused(const float* __restrict__ x, const int* __restrict__ sidx_p,
                          const float* __restrict__ sv, const float* __restrict__ ra,
                          const float* __restrict__ cs, const float* __restrict__ csh,
                          const float* __restrict__ b1, const float* __restrict__ b2,
                          const float* __restrict__ b3, const float* __restrict__ b4,
                          const _Float16* __restrict__ wsw, float* __restrict__ out)
{
    __shared__ __align__(16) _Float16 hbuf[32768];     // 128 px x 256 hid, 64 KB
    int t = threadIdx.x;
    int lane = t & 63, w = t >> 6, q = lane >> 4, ln = lane & 15;
    int pixbase = blockIdx.x * 128;
    int b = pixbase >> 14;                             // 16384 px per image
    int sidx = sidx_p[b];
    float dy = sv[2*sidx], dx = sv[2*sidx + 1];
    float ang = ra[sidx];
    float sn, cn;
    sincosf(ang, &sn, &cn);

    // stage coords into hbuf[p][0..32) (K padded with zeros; avoids 0*NaN poison)
    if (t < 128) {
        int p = t;
        float x0 = x[(pixbase + p)*2 + 0];
        float x1 = x[(pixbase + p)*2 + 1];
        float u = cn*x0 - sn*x1 + dx;
        float v = sn*x0 + cn*x1 + dy;
        half8 z;
#pragma unroll
        for (int i = 0; i < 8; ++i) z[i] = (_Float16)0.0f;
#pragma unroll
        for (int g = 0; g < 4; ++g) {
            int slot = (g + p) & 31;
            *(half8*)&hbuf[p*256 + slot*8] = z;
        }
        half2v uv;
        uv[0] = (_Float16)u; uv[1] = (_Float16)v;
        *(half2v*)&hbuf[p*256 + (p & 31)*8] = uv;
    }
    __syncthreads();

    const half8* wsw8 = (const half8*)wsw;
    do_layer<1>(wsw8,                b1, hbuf, w, q, ln, lane);   // layer 1 (K=32 padded)
    do_layer<8>(wsw8 + (W2OFF >> 3), b2, hbuf, w, q, ln, lane);   // layer 2
    do_layer<8>(wsw8 + (W3OFF >> 3), b3, hbuf, w, q, ln, lane);   // layer 3

    // layer 4: M=16 (3 real), each wave -> 32 pixels
    const half8* w4p = wsw8 + (W4OFF >> 3);
    f32x4 a4[2];
    a4[0] = (f32x4){0.f,0.f,0.f,0.f};
    a4[1] = (f32x4){0.f,0.f,0.f,0.f};
#pragma unroll
    for (int kkb = 0; kkb < 8; ++kkb) {
        half8 aw = w4p[kkb*64 + lane];
#pragma unroll
        for (int i = 0; i < 2; ++i) {
            int pixel = 16*(2*w + i) + ln;
            int slot  = (kkb*4 + q + pixel) & 31;
            half8 bf = *(const half8*)&hbuf[pixel*256 + slot*8];
            a4[i] = __builtin_amdgcn_mfma_f32_16x16x32_f16(aw, bf, a4[i], 0, 0, 0);
        }
    }
    if (q == 0) {                                      // rows 0..2 = output channels
        bool doc = (sidx != 0);
        float s0 = cs[sidx*3+0], s1 = cs[sidx*3+1], s2 = cs[sidx*3+2];
        float t0 = csh[sidx*3+0], t1 = csh[sidx*3+1], t2 = csh[sidx*3+2];
        float bb0 = b4[0], bb1 = b4[1], bb2 = b4[2];
#pragma unroll
        for (int i = 0; i < 2; ++i) {
            int gp = pixbase + 16*(2*w + i) + ln;
            float v0 = a4[i][0] + bb0;
            float v1 = a4[i][1] + bb1;
            float v2 = a4[i][2] + bb2;
            if (doc) { v0 = v0*s0 + t0; v1 = v1*s1 + t1; v2 = v2*s2 + t2; }
            out[gp*3 + 0] = v0;
            out[gp*3 + 1] = v1;
            out[gp*3 + 2] = v2;
        }
    }
}

extern "C" void kernel_launch(void* const* d_in, const int* in_sizes, int n_in,
                              void* d_out, int out_size, void* d_ws, size_t ws_size,
                              hipStream_t stream)
{
    const float* x    = (const float*)d_in[0];
    const int*   sidx = (const int*)  d_in[1];
    const float* sv   = (const float*)d_in[2];
    const float* ra   = (const float*)d_in[3];
    const float* cs   = (const float*)d_in[4];
    const float* csh  = (const float*)d_in[5];
    const float* W1   = (const float*)d_in[6];
    const float* b1   = (const float*)d_in[7];
    const float* W2   = (const float*)d_in[8];
    const float* b2   = (const float*)d_in[9];
    const float* W3   = (const float*)d_in[10];
    const float* b3   = (const float*)d_in[11];
    const float* W4   = (const float*)d_in[12];
    const float* b4   = (const float*)d_in[13];
    float* out = (float*)d_out;
    _Float16* wsw = (_Float16*)d_ws;

    inr_prep<<<SWTOT/256, 256, 0, stream>>>(W1, W2, W3, W4, sidx, sv, wsw, out + OUT_PIX*3);
    inr_fused<<<OUT_PIX/128, 256, 0, stream>>>(x, sidx, sv, ra, cs, csh,
                                               b1, b2, b3, b4, wsw, out);
}

// Round 5
// 144.666 us; speedup vs baseline: 1.6446x; 1.6446x over previous
//
#include <hip/hip_runtime.h>
#include <math.h>

typedef _Float16 half8  __attribute__((ext_vector_type(8)));
typedef _Float16 half4v __attribute__((ext_vector_type(4)));
typedef _Float16 half2v __attribute__((ext_vector_type(2)));
typedef float    f32x4  __attribute__((ext_vector_type(4)));

// swizzled-weight offsets in halfs inside d_ws
#define W1OFF 0        // 16 MT-tiles * 64 lanes * 8 = 8192 halfs (K padded 2->32)
#define W2OFF 8192     // 8 kkb * 16 MT * 64 * 8 = 65536
#define W3OFF 73728    // 65536
#define W4OFF 139264   // 8 kkb * 64 * 8 = 4096 (N padded 3->16)
#define SWTOT 143360
#define OUT_PIX (16*128*128)

// ---------------- prep: swizzle weights (fp32 -> f16 frag-contiguous) + dx/dy tail ----
__global__ void inr_prep(const float* __restrict__ W1, const float* __restrict__ W2,
                         const float* __restrict__ W3, const float* __restrict__ W4,
                         const int* __restrict__ sidx, const float* __restrict__ sv,
                         _Float16* __restrict__ wsw, float* __restrict__ outtail)
{
    int tid = blockIdx.x * 256 + threadIdx.x;
    if (tid < 16) {
        int si = sidx[tid];
        outtail[tid]      = sv[2*si + 1];   // dx = shift[:,1]
        outtail[16 + tid] = sv[2*si + 0];   // dy = shift[:,0]
    }
    if (tid >= SWTOT) return;
    int kind, rel;
    if      (tid < W2OFF) { kind = 0; rel = tid; }
    else if (tid < W3OFF) { kind = 1; rel = tid - W2OFF; }
    else if (tid < W4OFF) { kind = 2; rel = tid - W3OFF; }
    else                  { kind = 3; rel = tid - W4OFF; }
    int j    = rel & 7;
    int lane = (rel >> 3) & 63;
    int blk  = rel >> 9;
    int q = lane >> 4, ln = lane & 15;
    float val;
    if (kind == 3) {                       // W4: A[m][k] = W4[k][m], m<3 else 0
        int m = ln;
        int k = blk * 32 + q * 8 + j;
        val = (m < 3) ? W4[k*3 + m] : 0.0f;
    } else {
        int MT = blk & 15, kkb = blk >> 4;
        int m = MT*16 + ln;
        int k = kkb*32 + q*8 + j;
        if      (kind == 0) val = (k < 2) ? W1[k*256 + m] : 0.0f;
        else if (kind == 1) val = W2[k*256 + m];
        else                val = W3[k*256 + m];
    }
    wsw[tid] = (_Float16)val;
}

// ---------------- fused MLP ----------------
// LDS activation layout: granule-major.  Element (pixel, hid) lives at
//   hbuf[(hid>>3)*1024 + pixel*8 + (hid&7)]     (granule = 8 halfs = 16 B, 128 px)
template<int NKK>
__device__ __forceinline__ void do_layer(const half8* __restrict__ Asw,
                                         const float* __restrict__ bias,
                                         _Float16* hbuf, int w, int q, int ln, int lane)
{
    f32x4 acc[4][8];
#pragma unroll
    for (int mt = 0; mt < 4; ++mt)
#pragma unroll
        for (int nt = 0; nt < 8; ++nt)
            acc[mt][nt] = (f32x4){0.f, 0.f, 0.f, 0.f};

#pragma unroll
    for (int kkb = 0; kkb < NKK; ++kkb) {
        half8 aw[4];                                   // weights: global dwordx4, L2-hot
#pragma unroll
        for (int mt = 0; mt < 4; ++mt)
            aw[mt] = Asw[(kkb*16 + 4*w + mt)*64 + lane];
        half8 bf[8];                                   // activations: ds_read_b128, stride-16B
        int g = kkb*4 + q;
#pragma unroll
        for (int nt = 0; nt < 8; ++nt)
            bf[nt] = *(const half8*)&hbuf[g*1024 + (16*nt + ln)*8];
#pragma unroll
        for (int nt = 0; nt < 8; ++nt)
#pragma unroll
            for (int mt = 0; mt < 4; ++mt)
                acc[mt][nt] = __builtin_amdgcn_mfma_f32_16x16x32_f16(aw[mt], bf[nt], acc[mt][nt], 0, 0, 0);
    }
    __syncthreads();                                   // all reads of hbuf done
    // epilogue: bias + relu + f16 cast; lane holds 4 consecutive hids -> one b64 write
#pragma unroll
    for (int mt = 0; mt < 4; ++mt) {
        int hid0 = 64*w + 16*mt + 4*q;
        f32x4 bv = *(const f32x4*)&bias[hid0];
        int g = hid0 >> 3;
        int o = hid0 & 7;
#pragma unroll
        for (int nt = 0; nt < 8; ++nt) {
            int pixel = 16*nt + ln;
            f32x4 a = acc[mt][nt];
            half4v hv;
            hv[0] = (_Float16)fmaxf(a[0] + bv[0], 0.f);
            hv[1] = (_Float16)fmaxf(a[1] + bv[1], 0.f);
            hv[2] = (_Float16)fmaxf(a[2] + bv[2], 0.f);
            hv[3] = (_Float16)fmaxf(a[3] + bv[3], 0.f);
            *(half4v*)&hbuf[g*1024 + pixel*8 + o] = hv;
        }
    }
    __syncthreads();
}

__launch_bounds__(256, 2)
__global__ void inr_fused(const float* __restrict__ x, const int* __restrict__ sidx_p,
                          const float* __restrict__ sv, const float* __restrict__ ra,
                          const float* __restrict__ cs, const float* __restrict__ csh,
                          const float* __restrict__ b1, const float* __restrict__ b2,
                          const float* __restrict__ b3, const float* __restrict__ b4,
                          const _Float16* __restrict__ wsw, float* __restrict__ out)
{
    __shared__ __align__(16) _Float16 hbuf[32768];     // 128 px x 256 hid, 64 KB
    int t = threadIdx.x;
    int lane = t & 63, w = t >> 6, q = lane >> 4, ln = lane & 15;
    int pixbase = blockIdx.x * 128;
    int b = pixbase >> 14;                             // 16384 px per image
    int sidx = sidx_p[b];
    float dy = sv[2*sidx], dx = sv[2*sidx + 1];
    float ang = ra[sidx];
    float sn, cn;
    sincosf(ang, &sn, &cn);

    // stage coords: hids 0..31 (granules 0..3), zero-padded K, uv at hid 0,1
    if (t < 128) {
        int p = t;
        float x0 = x[(pixbase + p)*2 + 0];
        float x1 = x[(pixbase + p)*2 + 1];
        float u = cn*x0 - sn*x1 + dx;
        float v = sn*x0 + cn*x1 + dy;
        half8 z;
#pragma unroll
        for (int i = 0; i < 8; ++i) z[i] = (_Float16)0.0f;
#pragma unroll
        for (int g = 1; g < 4; ++g)
            *(half8*)&hbuf[g*1024 + p*8] = z;
        z[0] = (_Float16)u; z[1] = (_Float16)v;
        *(half8*)&hbuf[0*1024 + p*8] = z;
    }
    __syncthreads();

    const half8* wsw8 = (const half8*)wsw;
    do_layer<1>(wsw8,                b1, hbuf, w, q, ln, lane);   // layer 1 (K=32 padded)
    do_layer<8>(wsw8 + (W2OFF >> 3), b2, hbuf, w, q, ln, lane);   // layer 2
    do_layer<8>(wsw8 + (W3OFF >> 3), b3, hbuf, w, q, ln, lane);   // layer 3

    // layer 4: M=16 (3 real), each wave -> 32 pixels
    const half8* w4p = wsw8 + (W4OFF >> 3);
    f32x4 a4[2];
    a4[0] = (f32x4){0.f,0.f,0.f,0.f};
    a4[1] = (f32x4){0.f,0.f,0.f,0.f};
#pragma unroll
    for (int kkb = 0; kkb < 8; ++kkb) {
        half8 aw = w4p[kkb*64 + lane];
#pragma unroll
        for (int i = 0; i < 2; ++i) {
            int pixel = 16*(2*w + i) + ln;
            half8 bf = *(const half8*)&hbuf[(kkb*4 + q)*1024 + pixel*8];
            a4[i] = __builtin_amdgcn_mfma_f32_16x16x32_f16(aw, bf, a4[i], 0, 0, 0);
        }
    }
    if (q == 0) {                                      // rows 0..2 = output channels
        bool doc = (sidx != 0);
        float s0 = cs[sidx*3+0], s1 = cs[sidx*3+1], s2 = cs[sidx*3+2];
        float t0 = csh[sidx*3+0], t1 = csh[sidx*3+1], t2 = csh[sidx*3+2];
        float bb0 = b4[0], bb1 = b4[1], bb2 = b4[2];
#pragma unroll
        for (int i = 0; i < 2; ++i) {
            int gp = pixbase + 16*(2*w + i) + ln;
            float v0 = a4[i][0] + bb0;
            float v1 = a4[i][1] + bb1;
            float v2 = a4[i][2] + bb2;
            if (doc) { v0 = v0*s0 + t0; v1 = v1*s1 + t1; v2 = v2*s2 + t2; }
            out[gp*3 + 0] = v0;
            out[gp*3 + 1] = v1;
            out[gp*3 + 2] = v2;
        }
    }
}

extern "C" void kernel_launch(void* const* d_in, const int* in_sizes, int n_in,
                              void* d_out, int out_size, void* d_ws, size_t ws_size,
                              hipStream_t stream)
{
    const float* x    = (const float*)d_in[0];
    const int*   sidx = (const int*)  d_in[1];
    const float* sv   = (const float*)d_in[2];
    const float* ra   = (const float*)d_in[3];
    const float* cs   = (const float*)d_in[4];
    const float* csh  = (const float*)d_in[5];
    const float* W1   = (const float*)d_in[6];
    const float* b1   = (const float*)d_in[7];
    const float* W2   = (const float*)d_in[8];
    const float* b2   = (const float*)d_in[9];
    const float* W3   = (const float*)d_in[10];
    const float* b3   = (const float*)d_in[11];
    const float* W4   = (const float*)d_in[12];
    const float* b4   = (const float*)d_in[13];
    float* out = (float*)d_out;
    _Float16* wsw = (_Float16*)d_ws;

    inr_prep<<<SWTOT/256, 256, 0, stream>>>(W1, W2, W3, W4, sidx, sv, wsw, out + OUT_PIX*3);
    inr_fused<<<OUT_PIX/128, 256, 0, stream>>>(x, sidx, sv, ra, cs, csh,
                                               b1, b2, b3, b4, wsw, out);
}